// Round 8
// baseline (138.323 us; speedup 1.0000x reference)
//
#include <hip/hip_runtime.h>

// SpatialTransformer: per-batch 3x3 homography warp + bilinear sample of
// image channel 0. image: (B,128,128,3) f32, H: (B,3,3) f32,
// out: (B,128,128,1) f32. B = 2048.
//
// R8: one block per image, 512 threads, ch0 plane staged in LDS as fp16
// (32KB -> 4 blocks/CU vs R7's 2) so four blocks per CU pipeline their
// stage(memory)/compute(VALU) phases and HBM stays busy. Taps in fp16 are
// safe: they enter the output continuously (convex blend, error <= 2^-12).
// Coordinates stay bit-identical to R1 (exact IEEE divide, same op order)
// because the output is DISCONTINUOUS in x,y at clamp boundaries (R3).

#define IMG_H 128
#define IMG_W 128
#define NPIX  (IMG_H * IMG_W)    // 16384
#define NFLT  (NPIX * 3)         // 49152
#define TPB   512

typedef float    f32x4 __attribute__((ext_vector_type(4)));
typedef _Float16 f16x4 __attribute__((ext_vector_type(4)));

__global__ __launch_bounds__(TPB, 8) void st_warp_kernel(
    const float* __restrict__ img,   // B*128*128*3
    const float* __restrict__ Hm,    // B*9
    float* __restrict__ out)         // B*128*128
{
    __shared__ _Float16 shh[NPIX];   // ch0 plane in fp16, 32768 B

    const int b = blockIdx.x;
    const int t = threadIdx.x;
    const float* imb = img + (size_t)b * NFLT;

    const float* Hb = Hm + b * 9;    // uniform across block -> scalar loads
    const float h00 = Hb[0], h01 = Hb[1], h02 = Hb[2];
    const float h10 = Hb[3], h11 = Hb[4], h12 = Hb[5];
    const float h20 = Hb[6], h21 = Hb[7], h22 = Hb[8];

    // ---- stage: 4096 chunks of 12 floats -> 4 contiguous fp16 LDS values
    #pragma unroll
    for (int p = 0; p < 8; ++p) {
        const int c = t + p * TPB;               // chunk id, < 4096
        const float* src = imb + c * 12;         // 48B-aligned
        const f32x4 v0 = *reinterpret_cast<const f32x4*>(src);
        const f32x4 v1 = *reinterpret_cast<const f32x4*>(src + 4);
        const f32x4 v2 = *reinterpret_cast<const f32x4*>(src + 8);
        f16x4 w;
        w.x = (_Float16)v0.x;   // ch0 of px 4c+0
        w.y = (_Float16)v0.w;   // ch0 of px 4c+1
        w.z = (_Float16)v1.z;   // ch0 of px 4c+2
        w.w = (_Float16)v2.y;   // ch0 of px 4c+3
        *reinterpret_cast<f16x4*>(&shh[c * 4]) = w;   // 8B ds_write_b64
    }
    __syncthreads();

    const float step = 2.0f / 127.0f;
    float* outb = out + (size_t)b * NPIX;

    // j = t & 127 is invariant across the k-loop (TPB % 128 == 0)
    const int j = t & 127;
    const float xt = -1.0f + step * (float)j;
    const float txc = h00 * xt;      // hoisted: Tx = txc + h01*yt + h02
    const float tyc = h10 * xt;
    const float tzc = h20 * xt;

    #pragma unroll 1
    for (int k = 0; k < NPIX / TPB; ++k) {   // 32 iterations, 4 rows each
        const int n = t + k * TPB;
        const int i = n >> 7;

        // ---- coordinates (same rounding as R1: (a*b + c*d) + e) ----
        const float yt = -1.0f + step * (float)i;
        const float Tx = txc + h01 * yt + h02;
        const float Ty = tyc + h11 * yt + h12;
        const float Tz = tzc + h21 * yt + h22;
        const float x = (Tx / Tz + 1.0f) * 64.0f;   // exact IEEE divide
        const float y = (Ty / Tz + 1.0f) * 64.0f;

        int x0 = (int)fmaxf(fminf(floorf(x), 2.0e9f), -2.0e9f);
        int y0 = (int)fmaxf(fminf(floorf(y), 2.0e9f), -2.0e9f);
        int x1 = x0 + 1, y1 = y0 + 1;
        x0 = min(max(x0, 0), IMG_W - 1);
        x1 = min(max(x1, 0), IMG_W - 1);
        y0 = min(max(y0, 0), IMG_H - 1);
        y1 = min(max(y1, 0), IMG_H - 1);
        const int xl = min(x0, IMG_W - 2);   // [xl, xl+1] covers x0 and x1

        // ---- LDS gather (fp16 taps, continuous -> rounding is safe) ----
        const float lo0 = (float)shh[(y0 << 7) + xl];
        const float hi0 = (float)shh[(y0 << 7) + xl + 1];
        const float lo1 = (float)shh[(y1 << 7) + xl];
        const float hi1 = (float)shh[(y1 << 7) + xl + 1];
        const float Ia = (x0 > xl) ? hi0 : lo0;
        const float Ic = (x1 > xl) ? hi0 : lo0;
        const float Ib = (x0 > xl) ? hi1 : lo1;
        const float Id = (x1 > xl) ? hi1 : lo1;

        // ---- blend (weights from CLIPPED indices = ref semantics) ----
        const float x0f = (float)x0, x1f = (float)x1;
        const float y0f = (float)y0, y1f = (float)y1;
        const float wa = (x1f - x) * (y1f - y);
        const float wb = (x1f - x) * (y - y0f);
        const float wc = (x - x0f) * (y1f - y);
        const float wd = (x - x0f) * (y - y0f);

        __builtin_nontemporal_store(wa * Ia + wb * Ib + wc * Ic + wd * Id,
                                    outb + n);
    }
}

extern "C" void kernel_launch(void* const* d_in, const int* in_sizes, int n_in,
                              void* d_out, int out_size, void* d_ws, size_t ws_size,
                              hipStream_t stream) {
    const float* img = (const float*)d_in[0];   // (2048,128,128,3) f32
    const float* Hm  = (const float*)d_in[1];   // (2048,3,3) f32
    float* out = (float*)d_out;                 // (2048,128,128,1) f32

    const int B = in_sizes[1] / 9;              // 2048 blocks, 1 image each
    st_warp_kernel<<<B, TPB, 0, stream>>>(img, Hm, out);
}

// Round 9
// 124.517 us; speedup vs baseline: 1.1109x; 1.1109x over previous
//
#include <hip/hip_runtime.h>

// SpatialTransformer: per-batch 3x3 homography warp + bilinear sample of
// image channel 0. image: (B,128,128,3) f32, H: (B,3,3) f32,
// out: (B,128,128,1) f32. B = 2048.
//
// R9 = R7 (one block/image, 64KB f32 ch0 plane in LDS, bit-identical coord
// math, NT store) with ONE change: staging loads are now perfectly lane-
// coalesced (thread t loads float4 #(t+p*1024); a wave touches 16 cache
// lines per load instead of 48) and ch0 extraction scatters to LDS with
// 1-2 scalar ds_write_b32 per float4. For float4 at global float index f0,
// the first ch0 value lands at pixel (f0+2)/3 for every phase f0%3, with
// element {x,z,y} for phase {0,1,2}; phase 0 has a second ch0 (v.w).

#define IMG_H 128
#define IMG_W 128
#define NPIX  (IMG_H * IMG_W)    // 16384
#define NFLT  (NPIX * 3)         // 49152
#define TPB   1024

typedef float f32x4 __attribute__((ext_vector_type(4)));

__global__ __launch_bounds__(TPB, 8) void st_warp_kernel(
    const float* __restrict__ img,   // B*128*128*3
    const float* __restrict__ Hm,    // B*9
    float* __restrict__ out)         // B*128*128
{
    __shared__ float sh[NPIX];       // ch0 plane, 65536 B

    const int b = blockIdx.x;
    const int t = threadIdx.x;
    const float* imb = img + (size_t)b * NFLT;

    const float* Hb = Hm + b * 9;    // uniform across block -> scalar loads
    const float h00 = Hb[0], h01 = Hb[1], h02 = Hb[2];
    const float h10 = Hb[3], h11 = Hb[4], h12 = Hb[5];
    const float h20 = Hb[6], h21 = Hb[7], h22 = Hb[8];

    // ---- stage: 12288 float4s, lane-coalesced; scatter ch0 to LDS ----
    #pragma unroll
    for (int p = 0; p < NFLT / 4 / TPB; ++p) {   // 12 float4s per thread
        const int g  = t + p * TPB;              // float4 index (coalesced)
        const f32x4 v = *(reinterpret_cast<const f32x4*>(imb) + g);
        const int f0 = g * 4;                    // global float index of v.x
        const int m  = f0 % 3;                   // channel phase of v.x
        const int p0 = (f0 + 2) / 3;             // first ch0 pixel in span
        const float val = (m == 0) ? v.x : ((m == 1) ? v.z : v.y);
        sh[p0] = val;
        if (m == 0) sh[p0 + 1] = v.w;            // phase 0 covers 2 ch0 px
    }
    __syncthreads();

    const float step = 2.0f / 127.0f;
    float* outb = out + (size_t)b * NPIX;

    #pragma unroll 1
    for (int k = 0; k < NPIX / TPB; ++k) {   // 16 pixels/thread
        const int n = t + k * TPB;
        const int i = n >> 7;     // row: wave's 64 lanes share one row
        const int j = n & 127;    // col: consecutive lanes -> consecutive cols

        // ---- coordinates (bit-identical to reference) ----
        const float yt = -1.0f + step * (float)i;
        const float xt = -1.0f + step * (float)j;
        const float Tx = h00 * xt + h01 * yt + h02;
        const float Ty = h10 * xt + h11 * yt + h12;
        const float Tz = h20 * xt + h21 * yt + h22;
        const float x = (Tx / Tz + 1.0f) * 64.0f;   // exact IEEE divide
        const float y = (Ty / Tz + 1.0f) * 64.0f;

        int x0 = (int)fmaxf(fminf(floorf(x), 2.0e9f), -2.0e9f);
        int y0 = (int)fmaxf(fminf(floorf(y), 2.0e9f), -2.0e9f);
        int x1 = x0 + 1, y1 = y0 + 1;
        x0 = min(max(x0, 0), IMG_W - 1);
        x1 = min(max(x1, 0), IMG_W - 1);
        y0 = min(max(y0, 0), IMG_H - 1);
        y1 = min(max(y1, 0), IMG_H - 1);
        const int xl = min(x0, IMG_W - 2);   // [xl, xl+1] covers x0 and x1

        // ---- LDS gather: adjacent pair per row (compiler -> ds_read2) ----
        const float lo0 = sh[(y0 << 7) + xl];
        const float hi0 = sh[(y0 << 7) + xl + 1];
        const float lo1 = sh[(y1 << 7) + xl];
        const float hi1 = sh[(y1 << 7) + xl + 1];
        const float Ia = (x0 > xl) ? hi0 : lo0;
        const float Ic = (x1 > xl) ? hi0 : lo0;
        const float Ib = (x0 > xl) ? hi1 : lo1;
        const float Id = (x1 > xl) ? hi1 : lo1;

        // ---- blend (weights from CLIPPED indices = ref semantics) ----
        const float x0f = (float)x0, x1f = (float)x1;
        const float y0f = (float)y0, y1f = (float)y1;
        const float wa = (x1f - x) * (y1f - y);
        const float wb = (x1f - x) * (y - y0f);
        const float wc = (x - x0f) * (y1f - y);
        const float wd = (x - x0f) * (y - y0f);

        __builtin_nontemporal_store(wa * Ia + wb * Ib + wc * Ic + wd * Id,
                                    outb + n);
    }
}

extern "C" void kernel_launch(void* const* d_in, const int* in_sizes, int n_in,
                              void* d_out, int out_size, void* d_ws, size_t ws_size,
                              hipStream_t stream) {
    const float* img = (const float*)d_in[0];   // (2048,128,128,3) f32
    const float* Hm  = (const float*)d_in[1];   // (2048,3,3) f32
    float* out = (float*)d_out;                 // (2048,128,128,1) f32

    const int B = in_sizes[1] / 9;              // 2048 blocks, 1 image each
    st_warp_kernel<<<B, TPB, 0, stream>>>(img, Hm, out);
}